// Round 7
// baseline (528.363 us; speedup 1.0000x reference)
//
#include <hip/hip_runtime.h>
#include <hip/hip_cooperative_groups.h>
#include <math.h>

namespace cg = cooperative_groups;

#define C_ 256
#define H_ 512
#define W_ 512
#define HW_ (H_*W_)      // 262144
#define HD_ 128
#define WD_ 128
#define P_ (HD_*WD_)     // 16384
#define NN_ 32
#define GR_ 86
#define NSL_ 128
#define NBLK 512

// ws layout (float offsets)
#define XD_OFF     0ull
#define SDS_OFF    4194304ull
#define GT_OFF     8388608ull
#define GPART_OFF  8650752ull   // 128*7744 floats; dead after attn phase
#define DSTP_OFF   8650752ull   // aliases gpart: 256*64*18 (written in outds phase)
#define S_OFF      9641984ull   // 256
#define SPART_OFF  9642240ull   // 8192
#define NSQP_OFF   9650432ull   // 1024
#define GSUMP_OFF  9651456ull   // 512
#define BETA_OFF   9651968ull   // 256
#define M_OFF      9652224ull   // 256*88
#define SCALE_OFF  9674752ull   // 256

#define SMEM_FLOATS 9680        // 38720 B; max over phases (outds = 9680 exactly)

typedef float nfloat4 __attribute__((ext_vector_type(4)));

__device__ __forceinline__ void nt_store4(float4 v, float* p) {
    nfloat4 nv;
    nv.x = v.x; nv.y = v.y; nv.z = v.z; nv.w = v.w;
    __builtin_nontemporal_store(nv, (nfloat4*)p);
}

__device__ __forceinline__ float4 nt_load4(const float* p) {
    nfloat4 nv = __builtin_nontemporal_load((const nfloat4*)p);
    float4 v;
    v.x = nv.x; v.y = nv.y; v.z = nv.z; v.w = nv.w;
    return v;
}

__device__ __forceinline__ float wsum64(float v) {
#pragma unroll
    for (int off = 32; off > 0; off >>= 1) v += __shfl_down(v, off, 64);
    return v;
}

// ---- Phase A: maxpool + rowsum partial + noise copy + noise sumsq ----
__device__ __forceinline__ void pre_unit(
        int u, const float* __restrict__ x, const int* __restrict__ nidx,
        float* __restrict__ xd, float* __restrict__ outnf,
        float* __restrict__ Spart, float* __restrict__ nsqp, float* smem) {
    int c = u >> 5, seg = u & 31;
    int t = threadIdx.x;
    float* red = smem;
    int* snp = (int*)(smem + 4);
    if (t == 0) {
        int nn = -1;
        for (int n = 0; n < NN_; n++)
            if (nidx[n] == c) nn = n;
        *snp = nn;
    }
    __syncthreads();
    int n = *snp;
    int wd = t & 127;
    int hl = t >> 7;
    float ssum = 0.f, ss = 0.f;
    const float* xc = x + (size_t)c * HW_;
    float* nfc = outnf + (size_t)(n < 0 ? 0 : n) * HW_;
#pragma unroll
    for (int q = 0; q < 2; q++) {
        int hd = 4 * seg + hl + 2 * q;
        const float4* xr = (const float4*)(xc + (size_t)(4 * hd) * W_) + wd;
        float4 r0 = xr[0], r1 = xr[128], r2 = xr[256], r3 = xr[384];
        if (n >= 0) {
            float* nr = nfc + (size_t)(4 * hd) * W_ + 4 * wd;
            nt_store4(r0, nr);
            nt_store4(r1, nr + 512);
            nt_store4(r2, nr + 1024);
            nt_store4(r3, nr + 1536);
            ss += r0.x*r0.x + r0.y*r0.y + r0.z*r0.z + r0.w*r0.w
                + r1.x*r1.x + r1.y*r1.y + r1.z*r1.z + r1.w*r1.w
                + r2.x*r2.x + r2.y*r2.y + r2.z*r2.z + r2.w*r2.w
                + r3.x*r3.x + r3.y*r3.y + r3.z*r3.z + r3.w*r3.w;
        }
        float m0 = fmaxf(fmaxf(r0.x, r0.y), fmaxf(r0.z, r0.w));
        float m1 = fmaxf(fmaxf(r1.x, r1.y), fmaxf(r1.z, r1.w));
        float m2 = fmaxf(fmaxf(r2.x, r2.y), fmaxf(r2.z, r2.w));
        float m3 = fmaxf(fmaxf(r3.x, r3.y), fmaxf(r3.z, r3.w));
        float m = fmaxf(fmaxf(m0, m1), fmaxf(m2, m3));
        xd[(size_t)c * P_ + (size_t)hd * WD_ + wd] = m;
        ssum += m;
    }
    float tt = wsum64(ssum);
    int wid = t >> 6, ln = t & 63;
    if (ln == 0) red[wid] = tt;
    __syncthreads();
    if (t == 0) Spart[c * 32 + seg] = red[0] + red[1] + red[2] + red[3];
    if (n >= 0) {   // block-uniform
        __syncthreads();
        float t2 = wsum64(ss);
        if (ln == 0) red[wid] = t2;
        __syncthreads();
        if (t == 0) nsqp[n * 32 + seg] = red[0] + red[1] + red[2] + red[3];
    }
    __syncthreads();
}

// ---- Phase B unit: u<512 g-plane; 512..639 gram; 640 S-reduce ----
__device__ __forceinline__ void mid_unit(
        int u, const float* __restrict__ x, const int* __restrict__ nidx,
        const float* __restrict__ nsqp, const float* __restrict__ Spart,
        const float* __restrict__ xd,
        float* __restrict__ gt, float* __restrict__ gsump,
        float* __restrict__ gpart, float* __restrict__ S, float* smem) {
    int t = threadIdx.x;
    if (u < 512) {
        float* inv_ = smem;
        int* ncs = (int*)(smem + 32);
        float* red = smem + 64;
        float4* comb = (float4*)(smem + 128);
        if (t < NN_) {
            const float* np = nsqp + t * 32;
            float s = 0.f;
#pragma unroll
            for (int k = 0; k < 32; k++) s += np[k];
            inv_[t] = (1.f / 32.f) / fmaxf(sqrtf(s), 1e-12f);
            ncs[t] = nidx[t];
        }
        __syncthreads();
        int h = u >> 2, a = u & 3;
        int w = t & 127, half = t >> 7;
        size_t rowoff = (size_t)(4 * h + a) * W_ + 4 * w;
        float4 acc = make_float4(0.f, 0.f, 0.f, 0.f);
#pragma unroll
        for (int k = 0; k < 16; k++) {
            int n = half * 16 + k;
            float4 v = *(const float4*)(x + (size_t)ncs[n] * HW_ + rowoff);
            float iv = inv_[n];
            acc.x += v.x * iv; acc.y += v.y * iv;
            acc.z += v.z * iv; acc.w += v.w * iv;
        }
        comb[t] = acc;
        float gs = acc.x + acc.y + acc.z + acc.w;
        float tt = wsum64(gs);
        int wid = t >> 6, ln = t & 63;
        if (ln == 0) red[wid] = tt;
        __syncthreads();
        if (t == 0) gsump[u] = red[0] + red[1] + red[2] + red[3];
        if (t < 128) {
            float4 uu = comb[t], v2 = comb[t + 128];
            size_t pbase = (size_t)(a * 4) * P_ + h * WD_ + w;
            gt[pbase] = uu.x + v2.x;
            gt[pbase + P_] = uu.y + v2.y;
            gt[pbase + 2 * P_] = uu.z + v2.z;
            gt[pbase + 3 * P_] = uu.w + v2.w;
        }
        __syncthreads();
    } else if (u < 512 + NSL_) {
        int sl = u - 512;
        float (*As)[132] = (float(*)[132])smem;
        float (*Bs)[132] = (float(*)[132])(smem + 32 * 132);
        int tx = t & 15, ty = t >> 4;
        int p0 = sl * 128;
        float acc[6][6];
#pragma unroll
        for (int i = 0; i < 6; i++)
#pragma unroll
            for (int j = 0; j < 6; j++) acc[i][j] = 0.f;
        for (int ch = 0; ch < 4; ch++) {
            int pb = p0 + ch * 32;
            __syncthreads();
#pragma unroll
            for (int kk = 0; kk < 16; kk++) {
                int lin = kk * 256 + t;
                int row = lin >> 5;
                int pp = lin & 31;
                float av = 0.f, bv = 0.f;
                if (row < GR_) {
                    av = xd[(size_t)row * P_ + pb + pp];
                    bv = xd[(size_t)(85 + row) * P_ + pb + pp];
                }
                As[pp][row] = av;
                Bs[pp][row] = bv;
            }
            __syncthreads();
            for (int pp = 0; pp < 32; pp++) {
                float fa[6], fb[6];
#pragma unroll
                for (int i = 0; i < 6; i++) fa[i] = As[pp][6 * tx + i];
#pragma unroll
                for (int j = 0; j < 6; j++) fb[j] = Bs[pp][6 * ty + j];
#pragma unroll
                for (int ii = 0; ii < 6; ii++)
#pragma unroll
                    for (int jj = 0; jj < 6; jj++) acc[ii][jj] += fa[ii] * fb[jj];
            }
        }
        __syncthreads();
        float* gp = gpart + (size_t)sl * 7744;
#pragma unroll
        for (int ii = 0; ii < 6; ii++) {
            int ga = 6 * tx + ii;
            if (ga < GR_) {
#pragma unroll
                for (int jj = 0; jj < 6; jj++) {
                    int gb = 6 * ty + jj;
                    if (gb < GR_) gp[ga * 88 + gb] = acc[ii][jj];
                }
            }
        }
    } else {
        if (t < C_) {
            const float* sp = Spart + t * 32;
            float s = 0.f;
#pragma unroll
            for (int k = 0; k < 32; k++) s += sp[k];
            S[t] = s;
        }
        __syncthreads();
    }
}

// ---- Phase C: per-row softmax -> M, beta ----
__device__ __forceinline__ void attn_unit(
        int i, const int* __restrict__ labels, const float* __restrict__ wqkv,
        const float* __restrict__ bqkv, const float* __restrict__ gpart,
        const float* __restrict__ S, float* __restrict__ M,
        float* __restrict__ beta, float* smem) {
    int j = threadIdx.x;
    float* grow = smem;            // 86
    float* Mloc = smem + 96;       // 86
    float* red = smem + 192;       // 4
    float* bcp = smem + 196;       // 1
    int li = labels[i];
    if (li < 0) {
        if (j < GR_) M[i * 88 + j] = 0.f;
        if (j == 0) beta[i] = 0.f;
        return;   // device-fn return; block-uniform
    }
    int a = i / 3;
    if (j < GR_) {
        Mloc[j] = 0.f;
        const float* gp = gpart + (size_t)a * 88 + j;
        float s = 0.f;
#pragma unroll 8
        for (int sl = 0; sl < NSL_; sl++) s += gp[(size_t)sl * 7744];
        grow[j] = s;
    }
    __syncthreads();
    float wq = wqkv[i], bq = bqkv[i];
    int kidx = 256 + j;
    int bk = kidx / 3;
    float wk = wqkv[kidx], bkb = bqkv[kidx];
    int lj = labels[j];
    bool same = (lj == li);
    float score = -3.0e38f;
    if (same)
        score = wq * wk * grow[bk - 85] + wq * bkb * S[a] + bq * wk * S[bk] +
                16384.f * bq * bkb;
    int wid = j >> 6, ln = j & 63;
    float m = score;
#pragma unroll
    for (int off = 32; off > 0; off >>= 1) m = fmaxf(m, __shfl_down(m, off, 64));
    if (ln == 0) red[wid] = m;
    __syncthreads();
    if (j == 0) *bcp = fmaxf(fmaxf(red[0], red[1]), fmaxf(red[2], red[3]));
    __syncthreads();
    float mx = *bcp;
    float e = same ? expf(score - mx) : 0.f;
    __syncthreads();
    float t = wsum64(e);
    if (ln == 0) red[wid] = t;
    __syncthreads();
    if (j == 0) *bcp = red[0] + red[1] + red[2] + red[3];
    __syncthreads();
    float attn = e / *bcp;
    int vidx = 512 + j;
    int vr = vidx / 3 - 170;
    float wv = wqkv[vidx], bv = bqkv[vidx];
    __syncthreads();
    float bp = wsum64(attn * bv);
    if (ln == 0) red[wid] = bp;
    __syncthreads();
    if (j == 0) beta[i] = red[0] + red[1] + red[2] + red[3];
    atomicAdd(&Mloc[vr], attn * wv);
    __syncthreads();
    if (j < GR_) M[i * 88 + j] = Mloc[j];
}

// ---- Phase D: out_ds + fused stats partials ----
__device__ __forceinline__ void outds_unit(
        int px, int iy, const float* __restrict__ xd, const float* __restrict__ gt,
        const float* __restrict__ M, const float* __restrict__ beta,
        float* __restrict__ sds, float* __restrict__ dstp, float* smem) {
    float (*Mt)[88] = (float(*)[88])smem;          // 1408
    float* bt = smem + 1408;                       // 16
    float (*sdsL)[258] = (float(*)[258])(smem + 1424);  // 4128
    float (*gtsL)[258] = (float(*)[258])(smem + 5552);  // 4128
    int t = threadIdx.x;
    int p0 = px * 256;
    int i0 = iy * 16;
    __syncthreads();   // protect smem reuse across sequential units
    for (int idx = t; idx < 16 * 88; idx += 256)
        Mt[idx / 88][idx % 88] = M[(size_t)(i0 + idx / 88) * 88 + (idx % 88)];
    if (t < 16) bt[t] = beta[i0 + t];
#pragma unroll 4
    for (int ab = 0; ab < 16; ab++)
        gtsL[ab][t] = gt[(size_t)ab * P_ + p0 + t];
    __syncthreads();
    float acc[16];
#pragma unroll
    for (int ii = 0; ii < 16; ii++) acc[ii] = bt[ii];
    const float* xb = xd + (size_t)170 * P_ + p0 + t;
    for (int r = 0; r < 84; r += 4) {
        float x0 = xb[(size_t)r * P_];
        float x1 = xb[(size_t)(r + 1) * P_];
        float x2 = xb[(size_t)(r + 2) * P_];
        float x3 = xb[(size_t)(r + 3) * P_];
#pragma unroll
        for (int ii = 0; ii < 16; ii++) {
            float4 mv = *(const float4*)&Mt[ii][r];
            acc[ii] += mv.x * x0 + mv.y * x1 + mv.z * x2 + mv.w * x3;
        }
    }
    {
        float x0 = xb[(size_t)84 * P_];
        float x1 = xb[(size_t)85 * P_];
#pragma unroll
        for (int ii = 0; ii < 16; ii++)
            acc[ii] += Mt[ii][84] * x0 + Mt[ii][85] * x1;
    }
#pragma unroll
    for (int ii = 0; ii < 16; ii++) {
        sds[(size_t)(i0 + ii) * P_ + p0 + t] = acc[ii];
        sdsL[ii][t] = acc[ii];
    }
    __syncthreads();
    int ch = t & 15, ab = t >> 4;
    bool do1 = (t < 16), do2 = (t >= 16 && t < 32);
    float D = 0.f, sx = 0.f;
    for (int k = 0; k < 256; k++) {
        float sv = sdsL[ch][k];
        float gv = gtsL[ab][k];
        D += sv * gv;
        if (do1) sx += sv;
        if (do2) sx += sv * sv;
    }
    size_t base = ((size_t)(i0 + ch) * 64 + px) * 18;
    dstp[base + ab] = D;
    if (do1) dstp[base + 16] = sx;
    if (do2) dstp[base + 17] = sx;
}

// ---- Phase E: reduce partials -> scale[c] (threads 0..63) ----
__device__ __forceinline__ void sim_unit(
        int c, const float* __restrict__ dstp, const float* __restrict__ gsump,
        const float* __restrict__ wup, const float* __restrict__ bup,
        float* __restrict__ scale) {
    int t = threadIdx.x;   // 0..63
    const float* dp = dstp + ((size_t)c * 64 + t) * 18;
    float vals[19];
#pragma unroll
    for (int q = 0; q < 18; q++) vals[q] = dp[q];
    float gsl = 0.f;
#pragma unroll
    for (int k = 0; k < 8; k++) gsl += gsump[t + 64 * k];
    vals[18] = gsl;
#pragma unroll
    for (int q = 0; q < 19; q++) vals[q] = wsum64(vals[q]);
    if (t == 0) {
        float gs = vals[18];
        float wsm = 0.f, wsq = 0.f, dd = 0.f;
#pragma unroll
        for (int ab = 0; ab < 16; ab++) {
            float w = wup[c * 16 + ab];
            wsm += w;
            wsq += w * w;
            dd += w * vals[ab];
        }
        float s1 = vals[16], s2 = vals[17];
        float b = bup[c];
        float dot = dd + b * gs;
        float n2 = wsq * s2 + 2.f * b * wsm * s1 + (float)HW_ * b * b;
        float nrm = sqrtf(fmaxf(n2, 0.f));
        scale[c] = 1.f - dot / fmaxf(nrm, 1e-12f);
    }
}

// ---- Phase F (fused): block bid covers c=bid>>1, 64 pooled rows ----
__device__ __forceinline__ void final_block(
        int bid, const float* __restrict__ x, const float* __restrict__ sds,
        const float* __restrict__ wup, const float* __restrict__ bup,
        const float* __restrict__ scale, float* __restrict__ out) {
    int c = bid >> 1, hbase = (bid & 1) << 6;
    int t = threadIdx.x;
    int wq = t & 127, ysub = t >> 7;
    float b = bup[c], sc = scale[c];
    float4 wu0 = *(const float4*)(wup + c * 16 + ysub * 4);
    float4 wu1 = *(const float4*)(wup + c * 16 + (ysub + 2) * 4);
    const float* sdc = sds + (size_t)c * P_ + wq;
#pragma unroll 4
    for (int k = 0; k < 64; k++) {
        int hd = hbase + k;
        float sv = sdc[(size_t)hd * WD_];
        size_t xoff = ((size_t)c * H_ + 4 * hd + ysub) * W_ + 4 * wq;
        float4 x0 = nt_load4(x + xoff);
        float4 x1 = nt_load4(x + xoff + 2 * W_);
        float4 o0, o1;
        o0.x = sv * wu0.x + b + sc * x0.x;
        o0.y = sv * wu0.y + b + sc * x0.y;
        o0.z = sv * wu0.z + b + sc * x0.z;
        o0.w = sv * wu0.w + b + sc * x0.w;
        o1.x = sv * wu1.x + b + sc * x1.x;
        o1.y = sv * wu1.y + b + sc * x1.y;
        o1.z = sv * wu1.z + b + sc * x1.z;
        o1.w = sv * wu1.w + b + sc * x1.w;
        nt_store4(o0, out + xoff);
        nt_store4(o1, out + xoff + 2 * W_);
    }
}

// ---- Phase F (fallback): one (c,hd) row-pair per block ----
__device__ __forceinline__ void final_unit(
        int u, const float* __restrict__ x, const float* __restrict__ sds,
        const float* __restrict__ wup, const float* __restrict__ bup,
        const float* __restrict__ scale, float* __restrict__ out) {
    int c = u >> 7, hd = u & 127;
    int t = threadIdx.x;
    int wq = t & 127, ysub = t >> 7;
    float sv = sds[(size_t)c * P_ + (size_t)hd * WD_ + wq];
    float b = bup[c];
    float sc = scale[c];
    float4 wu0 = *(const float4*)(wup + c * 16 + ysub * 4);
    float4 wu1 = *(const float4*)(wup + c * 16 + (ysub + 2) * 4);
    size_t xoff = ((size_t)c * H_ + 4 * hd + ysub) * W_ + 4 * wq;
    float4 x0 = nt_load4(x + xoff);
    float4 x1 = nt_load4(x + xoff + 2 * W_);
    float4 o0, o1;
    o0.x = sv * wu0.x + b + sc * x0.x;
    o0.y = sv * wu0.y + b + sc * x0.y;
    o0.z = sv * wu0.z + b + sc * x0.z;
    o0.w = sv * wu0.w + b + sc * x0.w;
    o1.x = sv * wu1.x + b + sc * x1.x;
    o1.y = sv * wu1.y + b + sc * x1.y;
    o1.z = sv * wu1.z + b + sc * x1.z;
    o1.w = sv * wu1.w + b + sc * x1.w;
    nt_store4(o0, out + xoff);
    nt_store4(o1, out + xoff + 2 * W_);
}

// =========================== fused cooperative kernel ===========================
__global__ void __launch_bounds__(256) k_all(
        const float* __restrict__ x, const int* __restrict__ labels,
        const int* __restrict__ nidx, const float* __restrict__ wqkv,
        const float* __restrict__ bqkv, const float* __restrict__ wup,
        const float* __restrict__ bup, float* __restrict__ out,
        float* __restrict__ ws) {
    cg::grid_group grid = cg::this_grid();
    __shared__ float smem[SMEM_FLOATS];
    int bid = blockIdx.x;

    float* xd = ws + XD_OFF;
    float* sds = ws + SDS_OFF;
    float* gt = ws + GT_OFF;
    float* gpart = ws + GPART_OFF;
    float* dstp = ws + DSTP_OFF;
    float* S = ws + S_OFF;
    float* Spart = ws + SPART_OFF;
    float* nsqp = ws + NSQP_OFF;
    float* gsump = ws + GSUMP_OFF;
    float* beta = ws + BETA_OFF;
    float* M = ws + M_OFF;
    float* scale = ws + SCALE_OFF;
    float* outnf = out + (size_t)C_ * HW_;

    // Phase A: 8192 units, 16 per block
#pragma unroll 1
    for (int k = 0; k < 16; k++)
        pre_unit(bid + (k << 9), x, nidx, xd, outnf, Spart, nsqp, smem);
    grid.sync();

    // Phase B: 641 units
#pragma unroll 1
    for (int u = bid; u < 512 + NSL_ + 1; u += NBLK)
        mid_unit(u, x, nidx, nsqp, Spart, xd, gt, gsump, gpart, S, smem);
    grid.sync();

    // Phase C: 256 units
    if (bid < 256)
        attn_unit(bid, labels, wqkv, bqkv, gpart, S, M, beta, smem);
    grid.sync();

    // Phase D: 1024 units, 2 per block
#pragma unroll 1
    for (int u = bid; u < 1024; u += NBLK)
        outds_unit(u & 63, u >> 6, xd, gt, M, beta, sds, dstp, smem);
    grid.sync();

    // Phase E: 256 units
    if (bid < 256 && threadIdx.x < 64)
        sim_unit(bid, dstp, gsump, wup, bup, scale);
    grid.sync();

    // Phase F: 512 units, 1 per block
    final_block(bid, x, sds, wup, bup, scale, out);
}

// =========================== fallback wrappers ===========================
__global__ void __launch_bounds__(256) g_pre(
        const float* __restrict__ x, const int* __restrict__ nidx,
        float* __restrict__ xd, float* __restrict__ outnf,
        float* __restrict__ Spart, float* __restrict__ nsqp) {
    __shared__ float sm[8];
    pre_unit(blockIdx.x, x, nidx, xd, outnf, Spart, nsqp, sm);
}

__global__ void __launch_bounds__(256) g_mid(
        const float* __restrict__ x, const int* __restrict__ nidx,
        const float* __restrict__ nsqp, const float* __restrict__ Spart,
        const float* __restrict__ xd, float* __restrict__ gt,
        float* __restrict__ gsump, float* __restrict__ gpart,
        float* __restrict__ S) {
    __shared__ float sm[8448];
    mid_unit(blockIdx.x, x, nidx, nsqp, Spart, xd, gt, gsump, gpart, S, sm);
}

__global__ void __launch_bounds__(256) g_attn(
        const int* __restrict__ labels, const float* __restrict__ wqkv,
        const float* __restrict__ bqkv, const float* __restrict__ gpart,
        const float* __restrict__ S, float* __restrict__ M,
        float* __restrict__ beta) {
    __shared__ float sm[256];
    attn_unit(blockIdx.x, labels, wqkv, bqkv, gpart, S, M, beta, sm);
}

__global__ void __launch_bounds__(256) g_outds(
        const float* __restrict__ xd, const float* __restrict__ gt,
        const float* __restrict__ M, const float* __restrict__ beta,
        float* __restrict__ sds, float* __restrict__ dstp) {
    __shared__ float sm[SMEM_FLOATS];
    outds_unit(blockIdx.x & 63, blockIdx.x >> 6, xd, gt, M, beta, sds, dstp, sm);
}

__global__ void __launch_bounds__(64) g_sim(
        const float* __restrict__ dstp, const float* __restrict__ gsump,
        const float* __restrict__ wup, const float* __restrict__ bup,
        float* __restrict__ scale) {
    sim_unit(blockIdx.x, dstp, gsump, wup, bup, scale);
}

__global__ void __launch_bounds__(256) g_final(
        const float* __restrict__ x, const float* __restrict__ sds,
        const float* __restrict__ wup, const float* __restrict__ bup,
        const float* __restrict__ scale, float* __restrict__ out) {
    final_unit(blockIdx.x, x, sds, wup, bup, scale, out);
}

extern "C" void kernel_launch(void* const* d_in, const int* in_sizes, int n_in,
                              void* d_out, int out_size, void* d_ws, size_t ws_size,
                              hipStream_t stream) {
    const float* x = (const float*)d_in[0];
    const int* labels = (const int*)d_in[1];
    const int* nidx = (const int*)d_in[2];
    const float* wqkv = (const float*)d_in[3];
    const float* bqkv = (const float*)d_in[4];
    const float* wup = (const float*)d_in[5];
    const float* bup = (const float*)d_in[6];
    float* out = (float*)d_out;
    float* ws = (float*)d_ws;

    float* xd = ws + XD_OFF;
    float* sds = ws + SDS_OFF;
    float* gt = ws + GT_OFF;
    float* gpart = ws + GPART_OFF;
    float* dstp = ws + DSTP_OFF;
    float* S = ws + S_OFF;
    float* Spart = ws + SPART_OFF;
    float* nsqp = ws + NSQP_OFF;
    float* gsump = ws + GSUMP_OFF;
    float* beta = ws + BETA_OFF;
    float* M = ws + M_OFF;
    float* scale = ws + SCALE_OFF;
    float* outnf = out + (size_t)C_ * HW_;

    void* args[] = {(void*)&x, (void*)&labels, (void*)&nidx, (void*)&wqkv,
                    (void*)&bqkv, (void*)&wup, (void*)&bup, (void*)&out, (void*)&ws};
    hipError_t err = hipLaunchCooperativeKernel((void*)k_all, dim3(NBLK), dim3(256),
                                                args, 0, stream);
    if (err != hipSuccess) {
        // deterministic fallback: proven 6-kernel pipeline
        g_pre<<<C_ * 32, 256, 0, stream>>>(x, nidx, xd, outnf, Spart, nsqp);
        g_mid<<<512 + NSL_ + 1, 256, 0, stream>>>(x, nidx, nsqp, Spart, xd, gt, gsump, gpart, S);
        g_attn<<<256, 256, 0, stream>>>(labels, wqkv, bqkv, gpart, S, M, beta);
        g_outds<<<1024, 256, 0, stream>>>(xd, gt, M, beta, sds, dstp);
        g_sim<<<256, 64, 0, stream>>>(dstp, gsump, wup, bup, scale);
        g_final<<<32768, 256, 0, stream>>>(x, sds, wup, bup, scale, out);
    }
}

// Round 8
// 205.420 us; speedup vs baseline: 2.5721x; 2.5721x over previous
//
#include <hip/hip_runtime.h>
#include <math.h>

#define C_ 256
#define H_ 512
#define W_ 512
#define HW_ (H_*W_)      // 262144
#define HD_ 128
#define WD_ 128
#define P_ (HD_*WD_)     // 16384
#define NN_ 32
#define GR_ 86
#define NSL_ 128

// ws layout (float offsets)
#define XD_OFF     0ull
#define SDS_OFF    4194304ull
#define GT_OFF     8388608ull
#define GPART_OFF  8650752ull   // 128*7744 = 991232 floats; dead after k_attn
#define DSTP_OFF   8650752ull   // aliases gpart: 256*64*18 = 294912 (written by k_outds)
#define S_OFF      9641984ull   // 256
#define SPART_OFF  9642240ull   // 8192
#define NSQP_OFF   9650432ull   // 1024
#define GSUMP_OFF  9651456ull   // 128
#define BETA_OFF   9651968ull   // 256
#define M_OFF      9652224ull   // 256*88
#define SCALE_OFF  9674752ull   // 256

typedef float nfloat4 __attribute__((ext_vector_type(4)));

__device__ __forceinline__ void nt_store4(float4 v, float* p) {
    nfloat4 nv;
    nv.x = v.x; nv.y = v.y; nv.z = v.z; nv.w = v.w;
    __builtin_nontemporal_store(nv, (nfloat4*)p);
}

__device__ __forceinline__ float wsum64(float v) {
#pragma unroll
    for (int off = 32; off > 0; off >>= 1) v += __shfl_down(v, off, 64);
    return v;
}

// Fused: 4x4 maxpool -> xd ; rowsum partials -> Spart ; noise copy -> outnf ; noise sumsq -> nsqp
__global__ void __launch_bounds__(256) k_pre(
        const float* __restrict__ x, const int* __restrict__ nidx,
        float* __restrict__ xd, float* __restrict__ outnf,
        float* __restrict__ Spart, float* __restrict__ nsqp) {
    int b = blockIdx.x;
    int c = b >> 5, seg = b & 31;
    int t = threadIdx.x;
    __shared__ int sn;
    if (t == 0) {
        int nn = -1;
        for (int n = 0; n < NN_; n++)
            if (nidx[n] == c) nn = n;
        sn = nn;
    }
    __syncthreads();
    int n = sn;
    int wd = t & 127;
    int hl = t >> 7;
    float ssum = 0.f, ss = 0.f;
    const float* xc = x + (size_t)c * HW_;
    float* nfc = outnf + (size_t)(n < 0 ? 0 : n) * HW_;
#pragma unroll
    for (int q = 0; q < 2; q++) {
        int hd = 4 * seg + hl + 2 * q;
        const float4* xr = (const float4*)(xc + (size_t)(4 * hd) * W_) + wd;
        float4 r0 = xr[0], r1 = xr[128], r2 = xr[256], r3 = xr[384];
        if (n >= 0) {
            float* nr = nfc + (size_t)(4 * hd) * W_ + 4 * wd;
            nt_store4(r0, nr);
            nt_store4(r1, nr + 512);
            nt_store4(r2, nr + 1024);
            nt_store4(r3, nr + 1536);
            ss += r0.x*r0.x + r0.y*r0.y + r0.z*r0.z + r0.w*r0.w
                + r1.x*r1.x + r1.y*r1.y + r1.z*r1.z + r1.w*r1.w
                + r2.x*r2.x + r2.y*r2.y + r2.z*r2.z + r2.w*r2.w
                + r3.x*r3.x + r3.y*r3.y + r3.z*r3.z + r3.w*r3.w;
        }
        float m0 = fmaxf(fmaxf(r0.x, r0.y), fmaxf(r0.z, r0.w));
        float m1 = fmaxf(fmaxf(r1.x, r1.y), fmaxf(r1.z, r1.w));
        float m2 = fmaxf(fmaxf(r2.x, r2.y), fmaxf(r2.z, r2.w));
        float m3 = fmaxf(fmaxf(r3.x, r3.y), fmaxf(r3.z, r3.w));
        float m = fmaxf(fmaxf(m0, m1), fmaxf(m2, m3));
        xd[(size_t)c * P_ + (size_t)hd * WD_ + wd] = m;
        ssum += m;
    }
    __shared__ float red[4];
    float tt = wsum64(ssum);
    int wid = t >> 6, ln = t & 63;
    if (ln == 0) red[wid] = tt;
    __syncthreads();
    if (t == 0) Spart[c * 32 + seg] = red[0] + red[1] + red[2] + red[3];
    if (n >= 0) {   // block-uniform branch
        __syncthreads();
        float t2 = wsum64(ss);
        if (ln == 0) red[wid] = t2;
        __syncthreads();
        if (t == 0) nsqp[n * 32 + seg] = red[0] + red[1] + red[2] + red[3];
    }
}

// Merged mid kernel: bid<128 -> g-plane row h=bid ; 128<=bid<256 -> gram slice ; bid==256 -> S reduce
__global__ void __launch_bounds__(256) k_mid(
        const float* __restrict__ x, const int* __restrict__ nidx,
        const float* __restrict__ nsqp, const float* __restrict__ Spart,
        const float* __restrict__ xd,
        float* __restrict__ gt, float* __restrict__ gsump,
        float* __restrict__ gpart, float* __restrict__ S) {
    __shared__ float smem[2 * 32 * 132];   // 33 KB, shared across branch types
    int bid = blockIdx.x;
    int t = threadIdx.x;
    if (bid < 128) {
        // ---- g: gt[ab][hw] = (1/32) sum_n x[nc][(4h+a)*W+4w+b] / ||x_nc|| ----
        float* inv_ = smem;
        int* ncs = (int*)(smem + 32);
        float* red = smem + 64;
        if (t < NN_) {
            const float* np = nsqp + t * 32;
            float s = 0.f;
#pragma unroll
            for (int k = 0; k < 32; k++) s += np[k];
            inv_[t] = (1.f / 32.f) / fmaxf(sqrtf(s), 1e-12f);
            ncs[t] = nidx[t];
        }
        __syncthreads();
        int h = bid;
        int w = t & 127, a0 = t >> 7;
        float acc[2][4] = {{0.f,0.f,0.f,0.f},{0.f,0.f,0.f,0.f}};
#pragma unroll 4
        for (int n = 0; n < NN_; n++) {
            const float* base = x + (size_t)ncs[n] * HW_ + (size_t)(4 * h) * W_ + 4 * w;
            float4 va = *(const float4*)(base + (size_t)a0 * W_);
            float4 vb = *(const float4*)(base + (size_t)(a0 + 2) * W_);
            float iv = inv_[n];
            acc[0][0] += va.x * iv; acc[0][1] += va.y * iv;
            acc[0][2] += va.z * iv; acc[0][3] += va.w * iv;
            acc[1][0] += vb.x * iv; acc[1][1] += vb.y * iv;
            acc[1][2] += vb.z * iv; acc[1][3] += vb.w * iv;
        }
        float gs = 0.f;
#pragma unroll
        for (int q = 0; q < 2; q++) {
            int a = a0 + 2 * q;
#pragma unroll
            for (int bb = 0; bb < 4; bb++) {
                float g = acc[q][bb];
                gt[(size_t)(a * 4 + bb) * P_ + h * WD_ + w] = g;
                gs += g;
            }
        }
        float tt = wsum64(gs);
        int wid = t >> 6, ln = t & 63;
        if (ln == 0) red[wid] = tt;
        __syncthreads();
        if (t == 0) gsump[bid] = red[0] + red[1] + red[2] + red[3];
    } else if (bid < 128 + NSL_) {
        // ---- gram slice: gpart[sl][ga*88+gb] = sum_{p in slice} xd[ga][p]*xd[85+gb][p] ----
        int sl = bid - 128;
        float (*As)[132] = (float(*)[132])smem;
        float (*Bs)[132] = (float(*)[132])(smem + 32 * 132);
        int tx = t & 15, ty = t >> 4;
        int p0 = sl * 128;
        float acc[8][8];
#pragma unroll
        for (int i = 0; i < 8; i++)
#pragma unroll
            for (int j = 0; j < 8; j++) acc[i][j] = 0.f;
        for (int ch = 0; ch < 4; ch++) {
            int pb = p0 + ch * 32;
            __syncthreads();
#pragma unroll
            for (int kk = 0; kk < 16; kk++) {
                int lin = kk * 256 + t;
                int row = lin >> 5;
                int pp = lin & 31;
                float av = 0.f, bv = 0.f;
                if (row < GR_) {
                    av = xd[(size_t)row * P_ + pb + pp];
                    bv = xd[(size_t)(85 + row) * P_ + pb + pp];
                }
                As[pp][row] = av;
                Bs[pp][row] = bv;
            }
            __syncthreads();
            for (int pp = 0; pp < 32; pp++) {
                float4 fa0 = *(const float4*)&As[pp][8 * tx];
                float4 fa1 = *(const float4*)&As[pp][8 * tx + 4];
                float4 fb0 = *(const float4*)&Bs[pp][8 * ty];
                float4 fb1 = *(const float4*)&Bs[pp][8 * ty + 4];
                float fa[8] = {fa0.x, fa0.y, fa0.z, fa0.w, fa1.x, fa1.y, fa1.z, fa1.w};
                float fb[8] = {fb0.x, fb0.y, fb0.z, fb0.w, fb1.x, fb1.y, fb1.z, fb1.w};
#pragma unroll
                for (int ii = 0; ii < 8; ii++)
#pragma unroll
                    for (int jj = 0; jj < 8; jj++) acc[ii][jj] += fa[ii] * fb[jj];
            }
        }
        float* gp = gpart + (size_t)sl * 7744;
#pragma unroll
        for (int ii = 0; ii < 8; ii++) {
            int ga = 8 * tx + ii;
            if (ga < GR_) {
#pragma unroll
                for (int jj = 0; jj < 8; jj++) {
                    int gb = 8 * ty + jj;
                    if (gb < GR_) gp[ga * 88 + gb] = acc[ii][jj];
                }
            }
        }
    } else {
        // ---- S reduce ----
        if (t < C_) {
            const float* sp = Spart + t * 32;
            float s = 0.f;
#pragma unroll
            for (int k = 0; k < 32; k++) s += sp[k];
            S[t] = s;
        }
    }
}

// per-row softmax -> M[i][r], beta[i]; G-row reduced from gpart in prologue
__global__ void __launch_bounds__(256) k_attn(
        const int* __restrict__ labels, const float* __restrict__ wqkv,
        const float* __restrict__ bqkv, const float* __restrict__ gpart,
        const float* __restrict__ S, float* __restrict__ M,
        float* __restrict__ beta) {
    int i = blockIdx.x, j = threadIdx.x;
    __shared__ float grow[GR_];
    __shared__ float Mloc[GR_];
    __shared__ float red[4];
    __shared__ float bc;
    int li = labels[i];
    if (li < 0) {
        if (j < GR_) M[i * 88 + j] = 0.f;
        if (j == 0) beta[i] = 0.f;
        return;
    }
    int a = i / 3;
    if (j < GR_) {
        Mloc[j] = 0.f;
        const float* gp = gpart + (size_t)a * 88 + j;
        float s = 0.f;
#pragma unroll 8
        for (int sl = 0; sl < NSL_; sl++) s += gp[(size_t)sl * 7744];
        grow[j] = s;
    }
    __syncthreads();
    float wq = wqkv[i], bq = bqkv[i];
    int kidx = 256 + j;
    int bk = kidx / 3;
    float wk = wqkv[kidx], bkb = bqkv[kidx];
    int lj = labels[j];
    bool same = (lj == li);
    float score = -3.0e38f;
    if (same)
        score = wq * wk * grow[bk - 85] + wq * bkb * S[a] + bq * wk * S[bk] +
                16384.f * bq * bkb;
    int wid = j >> 6, ln = j & 63;
    float m = score;
#pragma unroll
    for (int off = 32; off > 0; off >>= 1) m = fmaxf(m, __shfl_down(m, off, 64));
    if (ln == 0) red[wid] = m;
    __syncthreads();
    if (j == 0) bc = fmaxf(fmaxf(red[0], red[1]), fmaxf(red[2], red[3]));
    __syncthreads();
    float mx = bc;
    float e = same ? expf(score - mx) : 0.f;
    __syncthreads();
    float t = wsum64(e);
    if (ln == 0) red[wid] = t;
    __syncthreads();
    if (j == 0) bc = red[0] + red[1] + red[2] + red[3];
    __syncthreads();
    float attn = e / bc;
    int vidx = 512 + j;
    int vr = vidx / 3 - 170;
    float wv = wqkv[vidx], bv = bqkv[vidx];
    __syncthreads();
    float bp = wsum64(attn * bv);
    if (ln == 0) red[wid] = bp;
    __syncthreads();
    if (j == 0) beta[i] = red[0] + red[1] + red[2] + red[3];
    atomicAdd(&Mloc[vr], attn * wv);
    __syncthreads();
    if (j < GR_) M[i * 88 + j] = Mloc[j];
}

// out_ds + fused per-channel stats partials. grid (64 p-tiles, 16 i-tiles), 256 threads.
__global__ void __launch_bounds__(256) k_outds(
        const float* __restrict__ xd, const float* __restrict__ gt,
        const float* __restrict__ M, const float* __restrict__ beta,
        float* __restrict__ sds, float* __restrict__ dstp) {
    __shared__ float Mt[16][88];
    __shared__ float bt[16];
    __shared__ float sdsL[16][258];
    __shared__ float gtsL[16][258];
    int t = threadIdx.x;
    int p0 = blockIdx.x * 256;
    int i0 = blockIdx.y * 16;
    for (int idx = t; idx < 16 * 88; idx += 256)
        Mt[idx / 88][idx % 88] = M[(size_t)(i0 + idx / 88) * 88 + (idx % 88)];
    if (t < 16) bt[t] = beta[i0 + t];
#pragma unroll 4
    for (int ab = 0; ab < 16; ab++)
        gtsL[ab][t] = gt[(size_t)ab * P_ + p0 + t];
    __syncthreads();
    float acc[16];
#pragma unroll
    for (int ii = 0; ii < 16; ii++) acc[ii] = bt[ii];
    const float* xb = xd + (size_t)170 * P_ + p0 + t;
    for (int r = 0; r < 84; r += 4) {
        float x0 = xb[(size_t)r * P_];
        float x1 = xb[(size_t)(r + 1) * P_];
        float x2 = xb[(size_t)(r + 2) * P_];
        float x3 = xb[(size_t)(r + 3) * P_];
#pragma unroll
        for (int ii = 0; ii < 16; ii++) {
            float4 mv = *(const float4*)&Mt[ii][r];
            acc[ii] += mv.x * x0 + mv.y * x1 + mv.z * x2 + mv.w * x3;
        }
    }
    {
        float x0 = xb[(size_t)84 * P_];
        float x1 = xb[(size_t)85 * P_];
#pragma unroll
        for (int ii = 0; ii < 16; ii++)
            acc[ii] += Mt[ii][84] * x0 + Mt[ii][85] * x1;
    }
#pragma unroll
    for (int ii = 0; ii < 16; ii++) {
        sds[(size_t)(i0 + ii) * P_ + p0 + t] = acc[ii];
        sdsL[ii][t] = acc[ii];
    }
    __syncthreads();
    int ch = t & 15, ab = t >> 4;
    bool do1 = (t < 16), do2 = (t >= 16 && t < 32);
    float D = 0.f, sx = 0.f;
    for (int k = 0; k < 256; k++) {
        float sv = sdsL[ch][k];
        float gv = gtsL[ab][k];
        D += sv * gv;
        if (do1) sx += sv;
        if (do2) sx += sv * sv;
    }
    size_t base = ((size_t)(i0 + ch) * 64 + blockIdx.x) * 18;
    dstp[base + ab] = D;
    if (do1) dstp[base + 16] = sx;
    if (do2) dstp[base + 17] = sx;
}

// reduce dstpart + gsump -> scale[c]. grid 256 blocks x 64 threads.
__global__ void __launch_bounds__(64) k_sim(
        const float* __restrict__ dstp, const float* __restrict__ gsump,
        const float* __restrict__ wup, const float* __restrict__ bup,
        float* __restrict__ scale) {
    int c = blockIdx.x, t = threadIdx.x;
    const float* dp = dstp + ((size_t)c * 64 + t) * 18;
    float vals[19];
#pragma unroll
    for (int q = 0; q < 18; q++) vals[q] = dp[q];
    vals[18] = gsump[t] + gsump[t + 64];
#pragma unroll
    for (int q = 0; q < 19; q++) vals[q] = wsum64(vals[q]);
    if (t == 0) {
        float gs = vals[18];
        float wsm = 0.f, wsq = 0.f, dd = 0.f;
#pragma unroll
        for (int ab = 0; ab < 16; ab++) {
            float w = wup[c * 16 + ab];
            wsm += w;
            wsq += w * w;
            dd += w * vals[ab];
        }
        float s1 = vals[16], s2 = vals[17];
        float b = bup[c];
        float dot = dd + b * gs;
        float n2 = wsq * s2 + 2.f * b * wsm * s1 + (float)HW_ * b * b;
        float nrm = sqrtf(fmaxf(n2, 0.f));
        scale[c] = 1.f - dot / fmaxf(nrm, 1e-12f);
    }
}

// out = s*w_up + b_up + scale * x.  grid 32768 blocks: c = bid>>7, hd = bid&127.
// PLAIN x loads (L3-resident hypothesis); NT stores for out.
__global__ void __launch_bounds__(256) k_final(
        const float* __restrict__ x, const float* __restrict__ sds,
        const float* __restrict__ wup, const float* __restrict__ bup,
        const float* __restrict__ scale, float* __restrict__ out) {
    int bid = blockIdx.x;
    int c = bid >> 7, hd = bid & 127;
    int t = threadIdx.x;
    int wq = t & 127, ysub = t >> 7;
    float sv = sds[(size_t)c * P_ + (size_t)hd * WD_ + wq];
    float b = bup[c];
    float sc = scale[c];
    float4 wu0 = *(const float4*)(wup + c * 16 + ysub * 4);
    float4 wu1 = *(const float4*)(wup + c * 16 + (ysub + 2) * 4);
    size_t xoff = ((size_t)c * H_ + 4 * hd + ysub) * W_ + 4 * wq;
    float4 x0 = *(const float4*)(x + xoff);
    float4 x1 = *(const float4*)(x + xoff + 2 * W_);
    float4 o0, o1;
    o0.x = sv * wu0.x + b + sc * x0.x;
    o0.y = sv * wu0.y + b + sc * x0.y;
    o0.z = sv * wu0.z + b + sc * x0.z;
    o0.w = sv * wu0.w + b + sc * x0.w;
    o1.x = sv * wu1.x + b + sc * x1.x;
    o1.y = sv * wu1.y + b + sc * x1.y;
    o1.z = sv * wu1.z + b + sc * x1.z;
    o1.w = sv * wu1.w + b + sc * x1.w;
    nt_store4(o0, out + xoff);
    nt_store4(o1, out + xoff + 2 * W_);
}

extern "C" void kernel_launch(void* const* d_in, const int* in_sizes, int n_in,
                              void* d_out, int out_size, void* d_ws, size_t ws_size,
                              hipStream_t stream) {
    const float* x = (const float*)d_in[0];
    const int* labels = (const int*)d_in[1];
    const int* nidx = (const int*)d_in[2];
    const float* wqkv = (const float*)d_in[3];
    const float* bqkv = (const float*)d_in[4];
    const float* wup = (const float*)d_in[5];
    const float* bup = (const float*)d_in[6];
    float* out = (float*)d_out;
    float* ws = (float*)d_ws;

    float* xd = ws + XD_OFF;
    float* sds = ws + SDS_OFF;
    float* gt = ws + GT_OFF;
    float* gpart = ws + GPART_OFF;
    float* dstp = ws + DSTP_OFF;
    float* S = ws + S_OFF;
    float* Spart = ws + SPART_OFF;
    float* nsqp = ws + NSQP_OFF;
    float* gsump = ws + GSUMP_OFF;
    float* beta = ws + BETA_OFF;
    float* M = ws + M_OFF;
    float* scale = ws + SCALE_OFF;
    float* outnf = out + (size_t)C_ * HW_;

    k_pre<<<C_ * 32, 256, 0, stream>>>(x, nidx, xd, outnf, Spart, nsqp);
    k_mid<<<128 + NSL_ + 1, 256, 0, stream>>>(x, nidx, nsqp, Spart, xd, gt, gsump, gpart, S);
    k_attn<<<256, 256, 0, stream>>>(labels, wqkv, bqkv, gpart, S, M, beta);
    k_outds<<<dim3(64, 16), 256, 0, stream>>>(xd, gt, M, beta, sds, dstp);
    k_sim<<<256, 64, 0, stream>>>(dstp, gsump, wup, bup, scale);
    k_final<<<32768, 256, 0, stream>>>(x, sds, wup, bup, scale, out);
}